// Round 1
// baseline (334.623 us; speedup 1.0000x reference)
//
#include <hip/hip_runtime.h>
#include <hip/hip_bf16.h>
#include <math.h>

#define NB 16384
#define ND 128
#define NH 512
#define NO 128
#define NE 8

using bf16x8 = __attribute__((ext_vector_type(8))) short;   // 8 bf16 (4 VGPRs)
using f32x4  = __attribute__((ext_vector_type(4))) float;

// ---- workspace layout (bytes) ----
#define WS_COUNTS   0u          // int[8]
#define WS_IMP      32u         // float[8]
#define WS_TOKID    256u        // int   [NE][NB]
#define WS_TOKGATE  524544u     // float [NE][NB]
#define WS_XBF      1048832u    // ushort[NB][ND]      (bf16 bits)
#define WS_W1T      5243136u    // ushort[NE][NH][ND]  (w1 transposed, bf16)
#define WS_W2T      6291712u    // ushort[NE][NO][NH]  (w2 transposed, bf16)
#define WS_WGD      7340288u    // double[ND][NE]

__device__ __forceinline__ unsigned f2bf(float f){           // RNE f32->bf16 bits
  unsigned u = __float_as_uint(f);
  u += 0x7FFFu + ((u >> 16) & 1u);
  return u >> 16;
}

// x -> bf16 (coalesced), plus one block converting w_gate -> f64
__global__ void cvt_x_kernel(const float* __restrict__ x, unsigned short* __restrict__ xb,
                             const float* __restrict__ wg, double* __restrict__ wgd){
  if (blockIdx.x == 1024){
    int t = threadIdx.x;
    #pragma unroll
    for (int i = 0; i < 4; ++i) wgd[t*4 + i] = (double)wg[t*4 + i];
    return;
  }
  int idx = (blockIdx.x*256 + threadIdx.x)*8;
  float4 a = *(const float4*)(x + idx);
  float4 b = *(const float4*)(x + idx + 4);
  uint4 o;
  o.x = f2bf(a.x) | (f2bf(a.y) << 16);
  o.y = f2bf(a.z) | (f2bf(a.w) << 16);
  o.z = f2bf(b.x) | (f2bf(b.y) << 16);
  o.w = f2bf(b.z) | (f2bf(b.w) << 16);
  *(uint4*)(xb + idx) = o;
}

// [E][R][C] f32 -> [E][C][R] bf16 via 64x64 LDS tiles
__global__ void transpose_bf16_kernel(const float* __restrict__ in, unsigned short* __restrict__ out,
                                      int R, int C){
  __shared__ unsigned short tile[64*72];                     // padded stride 72
  int e = blockIdx.z;
  int cbase = blockIdx.x*64, rbase = blockIdx.y*64;
  const float* ine = in + (size_t)e*R*C;
  unsigned short* oute = out + (size_t)e*R*C;
  int t = threadIdx.x;
  {
    int r = t >> 2, q = t & 3;
    const float4* src = (const float4*)(ine + (size_t)(rbase + r)*C + cbase + q*16);
    #pragma unroll
    for (int k = 0; k < 4; ++k){
      float4 v = src[k];
      uint2 p;
      p.x = f2bf(v.x) | (f2bf(v.y) << 16);
      p.y = f2bf(v.z) | (f2bf(v.w) << 16);
      *(uint2*)(tile + r*72 + q*16 + k*4) = p;
    }
  }
  __syncthreads();
  {
    int oc = t >> 2, q = t & 3;
    unsigned short vals[16];
    #pragma unroll
    for (int k = 0; k < 16; ++k) vals[k] = tile[(q*16 + k)*72 + oc];
    uint4 u0, u1;
    u0.x = vals[0]  | ((unsigned)vals[1]  << 16);
    u0.y = vals[2]  | ((unsigned)vals[3]  << 16);
    u0.z = vals[4]  | ((unsigned)vals[5]  << 16);
    u0.w = vals[6]  | ((unsigned)vals[7]  << 16);
    u1.x = vals[8]  | ((unsigned)vals[9]  << 16);
    u1.y = vals[10] | ((unsigned)vals[11] << 16);
    u1.z = vals[12] | ((unsigned)vals[13] << 16);
    u1.w = vals[14] | ((unsigned)vals[15] << 16);
    unsigned short* dst = oute + (size_t)(cbase + oc)*R + rbase + q*16;
    *(uint4*)(dst)     = u0;
    *(uint4*)(dst + 8) = u1;
  }
}

// f64-accurate logits, top-2 softmax, dispatch lists + importance
__global__ void gating_kernel(const float* __restrict__ x, const double* __restrict__ wgd,
                              int* __restrict__ counts, float* __restrict__ imp,
                              int* __restrict__ tok_ids, float* __restrict__ tok_gate){
  int tok = blockIdx.x*256 + threadIdx.x;
  double acc[NE];
  #pragma unroll
  for (int e = 0; e < NE; ++e) acc[e] = 0.0;
  const float4* xr = (const float4*)(x + (size_t)tok*ND);
  for (int i = 0; i < 32; ++i){
    float4 v = xr[i];
    const double* w = wgd + i*32;                            // 4 d-rows of [8]
    #pragma unroll
    for (int e = 0; e < NE; ++e)
      acc[e] += (double)v.x*w[e] + (double)v.y*w[8+e] + (double)v.z*w[16+e] + (double)v.w*w[24+e];
  }
  int i0 = 0; double l0 = acc[0];
  #pragma unroll
  for (int e = 1; e < NE; ++e) if (acc[e] > l0){ l0 = acc[e]; i0 = e; }
  int i1 = (i0 == 0) ? 1 : 0; double l1 = acc[i1];
  #pragma unroll
  for (int e = 0; e < NE; ++e) if (e != i0 && acc[e] > l1){ l1 = acc[e]; i1 = e; }
  float e1 = expf((float)(l1 - l0));
  float g0 = 1.0f/(1.0f + e1);
  float g1 = e1/(1.0f + e1);
  int s0 = atomicAdd(&counts[i0], 1);
  tok_ids [i0*NB + s0] = tok;
  tok_gate[i0*NB + s0] = g0;
  atomicAdd(&imp[i0], g0);
  int s1 = atomicAdd(&counts[i1], 1);
  tok_ids [i1*NB + s1] = tok;
  tok_gate[i1*NB + s1] = g1;
  atomicAdd(&imp[i1], g1);
}

// Grouped sparse experts: 64 tokens/block, fused (x@w1+b1).relu @ w2, bf16 MFMA 16x16x32.
__global__ __launch_bounds__(256) void expert_kernel(
    const unsigned short* __restrict__ xbf, const unsigned short* __restrict__ w1t,
    const unsigned short* __restrict__ w2t, const float* __restrict__ b1,
    const float* __restrict__ b2, const int* __restrict__ counts,
    const int* __restrict__ tok_ids, const float* __restrict__ tok_gate,
    float* __restrict__ y){
  __shared__ char lds[41472];
  char* xg  = lds;             // [64 tok][128 bf16], row stride 272B (16B pad)
  char* w1s = lds + 17408;     // [32 h][128 d bf16], stride 272B
  char* w2s = lds + 26112;     // [128 o][32 h bf16], stride 80B
  char* hts = lds + 36352;     // 4 waves x [16 tok][32 h bf16], stride 80B
  int e = blockIdx.y;
  int n_e = counts[e];
  int base = blockIdx.x*64;
  if (base >= n_e) return;
  int tid = threadIdx.x;
  const int*   tid_e = tok_ids  + e*NB;
  const float* tg_e  = tok_gate + e*NB;
  // gather x tile (bf16) into LDS
  {
    int row = tid >> 2, q = tid & 3;
    int slot = base + row;
    int tok = tid_e[slot < n_e ? slot : base];               // pad rows: any valid token (gate=0 later)
    const uint4* src = (const uint4*)(xbf + (size_t)tok*ND);
    char* dst = xg + row*272;
    #pragma unroll
    for (int i = 0; i < 4; ++i){ int c = q*4 + i; *(uint4*)(dst + c*16) = src[c]; }
  }
  __syncthreads();
  int wid = tid >> 6, lane = tid & 63, l15 = lane & 15, lg = lane >> 4;
  char* htw = hts + wid*1280;
  const f32x4 fzero = {0.f, 0.f, 0.f, 0.f};
  f32x4 yacc[8];
  #pragma unroll
  for (int ot = 0; ot < 8; ++ot) yacc[ot] = fzero;
  bf16x8 xfrag[4];                                           // B-operand of stage 1 (persistent)
  #pragma unroll
  for (int k = 0; k < 4; ++k)
    xfrag[k] = *(const bf16x8*)(xg + (wid*16 + l15)*272 + k*64 + lg*16);
  const unsigned short* w1e = w1t + e*NH*ND;
  const unsigned short* w2e = w2t + e*NO*NH;
  for (int hc = 0; hc < 16; ++hc){                           // 32 h per chunk
    __syncthreads();
    { // stage w1^T chunk [32h][128d]
      int row = tid >> 3, q = tid & 7;
      const uint4* src = (const uint4*)(w1e + (size_t)(hc*32 + row)*ND);
      char* dst = w1s + row*272;
      *(uint4*)(dst + (q*2+0)*16) = src[q*2+0];
      *(uint4*)(dst + (q*2+1)*16) = src[q*2+1];
    }
    { // stage w2^T chunk [128o][32h]
      int row = tid >> 1, q = tid & 1;
      const uint4* src = (const uint4*)(w2e + (size_t)row*NH + hc*32);
      char* dst = w2s + row*80;
      *(uint4*)(dst + (q*2+0)*16) = src[q*2+0];
      *(uint4*)(dst + (q*2+1)*16) = src[q*2+1];
    }
    __syncthreads();
    // stage 1: h^T[16h x 16tok] = w1^T @ x^T ; D: tok = lane&15, h = 4*(lane>>4)+reg
    #pragma unroll
    for (int hs = 0; hs < 2; ++hs){
      f32x4 hacc = fzero;
      #pragma unroll
      for (int k = 0; k < 4; ++k){
        bf16x8 a = *(const bf16x8*)(w1s + (hs*16 + l15)*272 + k*64 + lg*16);
        hacc = __builtin_amdgcn_mfma_f32_16x16x32_bf16(a, xfrag[k], hacc, 0, 0, 0);
      }
      float4 b1v = *(const float4*)(b1 + e*NH + hc*32 + hs*16 + lg*4);
      float v0 = fmaxf(hacc[0] + b1v.x, 0.f);
      float v1 = fmaxf(hacc[1] + b1v.y, 0.f);
      float v2 = fmaxf(hacc[2] + b1v.z, 0.f);
      float v3 = fmaxf(hacc[3] + b1v.w, 0.f);
      uint2 p;
      p.x = f2bf(v0) | (f2bf(v1) << 16);
      p.y = f2bf(v2) | (f2bf(v3) << 16);
      *(uint2*)(htw + l15*80 + hs*32 + lg*8) = p;            // ht[tok][h-linear]
    }
    // stage 2: y[16tok x 128o] += relu(h) @ w2 ; A from ht, B from w2s (same k-mapping)
    bf16x8 afrag = *(const bf16x8*)(htw + l15*80 + lg*16);
    #pragma unroll
    for (int ot = 0; ot < 8; ++ot){
      bf16x8 bfrag = *(const bf16x8*)(w2s + (ot*16 + l15)*80 + lg*16);
      yacc[ot] = __builtin_amdgcn_mfma_f32_16x16x32_bf16(afrag, bfrag, yacc[ot], 0, 0, 0);
    }
  }
  // epilogue: D: o = ot*16 + (lane&15), tok = 4*(lane>>4)+reg ; coalesced gate-scaled atomics
  float b2v[8];
  #pragma unroll
  for (int ot = 0; ot < 8; ++ot) b2v[ot] = b2[e*NO + ot*16 + l15];
  int s4 = base + wid*16 + lg*4;
  #pragma unroll
  for (int r = 0; r < 4; ++r){
    int slot = s4 + r;
    if (slot < n_e){
      int tokg = tid_e[slot];
      float g  = tg_e[slot];
      float* yrow = y + (size_t)tokg*NO + l15;
      #pragma unroll
      for (int ot = 0; ot < 8; ++ot)
        atomicAdd(yrow + ot*16, (yacc[ot][r] + b2v[ot]) * g);
    }
  }
}

__global__ void loss_kernel(const int* __restrict__ counts, const float* __restrict__ imp,
                            float* __restrict__ out){
  if (threadIdx.x != 0) return;
  double si = 0, sqi = 0, sl = 0, sql = 0;
  for (int e = 0; e < NE; ++e){
    double a = imp[e];
    double b = (double)counts[e];
    si += a; sqi += a*a; sl += b; sql += b*b;
  }
  double mi = si/8.0, vi = (sqi - 8.0*mi*mi)/7.0;
  double ml = sl/8.0, vl = (sql - 8.0*ml*ml)/7.0;
  out[NB*NO] = (float)(vi/(mi*mi + 1e-10) + vl/(ml*ml + 1e-10));
}

extern "C" void kernel_launch(void* const* d_in, const int* in_sizes, int n_in,
                              void* d_out, int out_size, void* d_ws, size_t ws_size,
                              hipStream_t stream){
  (void)in_sizes; (void)n_in; (void)out_size; (void)ws_size;
  const float* x  = (const float*)d_in[0];
  const float* wg = (const float*)d_in[1];
  const float* w1 = (const float*)d_in[2];
  const float* b1 = (const float*)d_in[3];
  const float* w2 = (const float*)d_in[4];
  const float* b2 = (const float*)d_in[5];
  float* out = (float*)d_out;
  char* ws = (char*)d_ws;
  int*            counts   = (int*)(ws + WS_COUNTS);
  float*          imp      = (float*)(ws + WS_IMP);
  int*            tok_ids  = (int*)(ws + WS_TOKID);
  float*          tok_gate = (float*)(ws + WS_TOKGATE);
  unsigned short* xbf      = (unsigned short*)(ws + WS_XBF);
  unsigned short* w1t      = (unsigned short*)(ws + WS_W1T);
  unsigned short* w2t      = (unsigned short*)(ws + WS_W2T);
  double*         wgd      = (double*)(ws + WS_WGD);

  hipMemsetAsync(d_out, 0, (size_t)(NB*NO + 1)*sizeof(float), stream);
  hipMemsetAsync(d_ws, 0, 256, stream);
  cvt_x_kernel<<<1025, 256, 0, stream>>>(x, xbf, wg, wgd);
  transpose_bf16_kernel<<<dim3(8, 2, NE), 256, 0, stream>>>(w1, w1t, ND, NH);
  transpose_bf16_kernel<<<dim3(2, 8, NE), 256, 0, stream>>>(w2, w2t, NH, NO);
  gating_kernel<<<NB/256, 256, 0, stream>>>(x, wgd, counts, imp, tok_ids, tok_gate);
  expert_kernel<<<dim3(NB/64, NE), 256, 0, stream>>>(xbf, w1t, w2t, b1, b2,
                                                     counts, tok_ids, tok_gate, out);
  loss_kernel<<<1, 64, 0, stream>>>(counts, imp, out);
}

// Round 2
// 71.548 us; speedup vs baseline: 4.6769x; 4.6769x over previous
//
#include <hip/hip_runtime.h>
#include <hip/hip_bf16.h>
#include <math.h>

#define NB 16384
#define ND 128
#define NH 512
#define NO 128
#define NE 8
#define CPAD 32   // pad experts to 128B (32 ints/floats) for independent cache lines

using bf16x8 = __attribute__((ext_vector_type(8))) short;   // 8 bf16 (4 VGPRs)
using f32x4  = __attribute__((ext_vector_type(4))) float;

// ---- workspace layout (bytes) ----
#define WS_COUNTS   0u          // int  [NE*CPAD]   (padded)
#define WS_IMP      1024u       // float[NE*CPAD]   (padded)
#define WS_TOKID    2048u       // int   [NE][NB]
#define WS_TOKGATE  526336u     // float [NE][NB]
#define WS_XBF      1050624u    // ushort[NB][ND]      (bf16 bits)
#define WS_W1T      5244928u    // ushort[NE][NH][ND]  (w1 transposed, bf16)
#define WS_W2T      6293504u    // ushort[NE][NO][NH]  (w2 transposed, bf16)

__device__ __forceinline__ unsigned f2bf(float f){           // RNE f32->bf16 bits
  unsigned u = __float_as_uint(f);
  u += 0x7FFFu + ((u >> 16) & 1u);
  return u >> 16;
}

// Fused gating + x->bf16. 4 lanes per token, 64 tokens per block.
// f64 logits (products exact) so top-2 selection matches the np reference.
__global__ __launch_bounds__(256) void gating_kernel(
    const float* __restrict__ x, const float* __restrict__ wg,
    unsigned short* __restrict__ xbf,
    int* __restrict__ counts, float* __restrict__ imp,
    int* __restrict__ tok_ids, float* __restrict__ tok_gate){
  __shared__ int   lcnt[NE];
  __shared__ float limp[NE];
  __shared__ int   lbase[NE];
  int tid = threadIdx.x;
  if (tid < NE){ lcnt[tid] = 0; limp[tid] = 0.f; }
  __syncthreads();
  int tok  = blockIdx.x*64 + (tid >> 2);
  int part = tid & 3;
  const float4* xr4 = (const float4*)(x + (size_t)tok*ND);
  double acc[NE];
  #pragma unroll
  for (int e = 0; e < NE; ++e) acc[e] = 0.0;
  #pragma unroll
  for (int j = 0; j < 8; ++j){
    int f4 = part + j*4;                       // float4 index within the row
    float4 v = xr4[f4];
    // emit bf16 copy of x (coalesced 8B/lane)
    uint2 p;
    p.x = f2bf(v.x) | (f2bf(v.y) << 16);
    p.y = f2bf(v.z) | (f2bf(v.w) << 16);
    *(uint2*)(xbf + (size_t)tok*ND + f4*4) = p;
    // accumulate logits in f64
    const float4* wr = (const float4*)(wg + f4*32);
    float vm[4] = {v.x, v.y, v.z, v.w};
    #pragma unroll
    for (int m = 0; m < 4; ++m){
      float4 wa = wr[2*m], wb = wr[2*m+1];
      double d = (double)vm[m];
      acc[0] += d*(double)wa.x; acc[1] += d*(double)wa.y;
      acc[2] += d*(double)wa.z; acc[3] += d*(double)wa.w;
      acc[4] += d*(double)wb.x; acc[5] += d*(double)wb.y;
      acc[6] += d*(double)wb.z; acc[7] += d*(double)wb.w;
    }
  }
  // reduce the 4 lane-partials
  #pragma unroll
  for (int e = 0; e < NE; ++e){
    acc[e] += __shfl_xor(acc[e], 1);
    acc[e] += __shfl_xor(acc[e], 2);
  }
  int i0 = 0, i1 = 0, s0 = 0, s1 = 0;
  float g0 = 0.f, g1 = 0.f;
  if (part == 0){
    double l0 = acc[0];
    #pragma unroll
    for (int e = 1; e < NE; ++e) if (acc[e] > l0){ l0 = acc[e]; i0 = e; }
    i1 = (i0 == 0) ? 1 : 0;
    double l1 = acc[i1];
    #pragma unroll
    for (int e = 0; e < NE; ++e) if (e != i0 && acc[e] > l1){ l1 = acc[e]; i1 = e; }
    float e1 = expf((float)(l1 - l0));
    g0 = 1.0f/(1.0f + e1);
    g1 = e1/(1.0f + e1);
    s0 = atomicAdd(&lcnt[i0], 1);
    s1 = atomicAdd(&lcnt[i1], 1);
    atomicAdd(&limp[i0], g0);
    atomicAdd(&limp[i1], g1);
  }
  __syncthreads();
  if (tid < NE){
    lbase[tid] = atomicAdd(&counts[tid*CPAD], lcnt[tid]);
    atomicAdd(&imp[tid*CPAD], limp[tid]);
  }
  __syncthreads();
  if (part == 0){
    int p0 = lbase[i0] + s0;
    tok_ids [i0*NB + p0] = tok;
    tok_gate[i0*NB + p0] = g0;
    int p1 = lbase[i1] + s1;
    tok_ids [i1*NB + p1] = tok;
    tok_gate[i1*NB + p1] = g1;
  }
}

// [E][R][C] f32 -> [E][C][R] bf16 via 64x64 LDS tiles
__global__ void transpose_bf16_kernel(const float* __restrict__ in, unsigned short* __restrict__ out,
                                      int R, int C){
  __shared__ unsigned short tile[64*72];                     // padded stride 72
  int e = blockIdx.z;
  int cbase = blockIdx.x*64, rbase = blockIdx.y*64;
  const float* ine = in + (size_t)e*R*C;
  unsigned short* oute = out + (size_t)e*R*C;
  int t = threadIdx.x;
  {
    int r = t >> 2, q = t & 3;
    const float4* src = (const float4*)(ine + (size_t)(rbase + r)*C + cbase + q*16);
    #pragma unroll
    for (int k = 0; k < 4; ++k){
      float4 v = src[k];
      uint2 p;
      p.x = f2bf(v.x) | (f2bf(v.y) << 16);
      p.y = f2bf(v.z) | (f2bf(v.w) << 16);
      *(uint2*)(tile + r*72 + q*16 + k*4) = p;
    }
  }
  __syncthreads();
  {
    int oc = t >> 2, q = t & 3;
    unsigned short vals[16];
    #pragma unroll
    for (int k = 0; k < 16; ++k) vals[k] = tile[(q*16 + k)*72 + oc];
    uint4 u0, u1;
    u0.x = vals[0]  | ((unsigned)vals[1]  << 16);
    u0.y = vals[2]  | ((unsigned)vals[3]  << 16);
    u0.z = vals[4]  | ((unsigned)vals[5]  << 16);
    u0.w = vals[6]  | ((unsigned)vals[7]  << 16);
    u1.x = vals[8]  | ((unsigned)vals[9]  << 16);
    u1.y = vals[10] | ((unsigned)vals[11] << 16);
    u1.z = vals[12] | ((unsigned)vals[13] << 16);
    u1.w = vals[14] | ((unsigned)vals[15] << 16);
    unsigned short* dst = oute + (size_t)(cbase + oc)*R + rbase + q*16;
    *(uint4*)(dst)     = u0;
    *(uint4*)(dst + 8) = u1;
  }
}

// Grouped sparse experts: 64 tokens/block, fused (x@w1+b1).relu @ w2, bf16 MFMA 16x16x32.
__global__ __launch_bounds__(256) void expert_kernel(
    const unsigned short* __restrict__ xbf, const unsigned short* __restrict__ w1t,
    const unsigned short* __restrict__ w2t, const float* __restrict__ b1,
    const float* __restrict__ b2, const int* __restrict__ counts,
    const int* __restrict__ tok_ids, const float* __restrict__ tok_gate,
    float* __restrict__ y){
  __shared__ char lds[41472];
  char* xg  = lds;             // [64 tok][128 bf16], row stride 272B (16B pad)
  char* w1s = lds + 17408;     // [32 h][128 d bf16], stride 272B
  char* w2s = lds + 26112;     // [128 o][32 h bf16], stride 80B
  char* hts = lds + 36352;     // 4 waves x [16 tok][32 h bf16], stride 80B
  int e = blockIdx.y;
  int n_e = counts[e*CPAD];
  int base = blockIdx.x*64;
  if (base >= n_e) return;
  int tid = threadIdx.x;
  const int*   tid_e = tok_ids  + e*NB;
  const float* tg_e  = tok_gate + e*NB;
  // gather x tile (bf16) into LDS
  {
    int row = tid >> 2, q = tid & 3;
    int slot = base + row;
    int tok = tid_e[slot < n_e ? slot : base];               // pad rows: any valid token (gate=0 later)
    const uint4* src = (const uint4*)(xbf + (size_t)tok*ND);
    char* dst = xg + row*272;
    #pragma unroll
    for (int i = 0; i < 4; ++i){ int c = q*4 + i; *(uint4*)(dst + c*16) = src[c]; }
  }
  __syncthreads();
  int wid = tid >> 6, lane = tid & 63, l15 = lane & 15, lg = lane >> 4;
  char* htw = hts + wid*1280;
  const f32x4 fzero = {0.f, 0.f, 0.f, 0.f};
  f32x4 yacc[8];
  #pragma unroll
  for (int ot = 0; ot < 8; ++ot) yacc[ot] = fzero;
  bf16x8 xfrag[4];                                           // B-operand of stage 1 (persistent)
  #pragma unroll
  for (int k = 0; k < 4; ++k)
    xfrag[k] = *(const bf16x8*)(xg + (wid*16 + l15)*272 + k*64 + lg*16);
  const unsigned short* w1e = w1t + e*NH*ND;
  const unsigned short* w2e = w2t + e*NO*NH;
  for (int hc = 0; hc < 16; ++hc){                           // 32 h per chunk
    __syncthreads();
    { // stage w1^T chunk [32h][128d]
      int row = tid >> 3, q = tid & 7;
      const uint4* src = (const uint4*)(w1e + (size_t)(hc*32 + row)*ND);
      char* dst = w1s + row*272;
      *(uint4*)(dst + (q*2+0)*16) = src[q*2+0];
      *(uint4*)(dst + (q*2+1)*16) = src[q*2+1];
    }
    { // stage w2^T chunk [128o][32h]
      int row = tid >> 1, q = tid & 1;
      const uint4* src = (const uint4*)(w2e + (size_t)row*NH + hc*32);
      char* dst = w2s + row*80;
      *(uint4*)(dst + (q*2+0)*16) = src[q*2+0];
      *(uint4*)(dst + (q*2+1)*16) = src[q*2+1];
    }
    __syncthreads();
    // stage 1: h^T[16h x 16tok] = w1^T @ x^T ; D: tok = lane&15, h = 4*(lane>>4)+reg
    #pragma unroll
    for (int hs = 0; hs < 2; ++hs){
      f32x4 hacc = fzero;
      #pragma unroll
      for (int k = 0; k < 4; ++k){
        bf16x8 a = *(const bf16x8*)(w1s + (hs*16 + l15)*272 + k*64 + lg*16);
        hacc = __builtin_amdgcn_mfma_f32_16x16x32_bf16(a, xfrag[k], hacc, 0, 0, 0);
      }
      float4 b1v = *(const float4*)(b1 + e*NH + hc*32 + hs*16 + lg*4);
      float v0 = fmaxf(hacc[0] + b1v.x, 0.f);
      float v1 = fmaxf(hacc[1] + b1v.y, 0.f);
      float v2 = fmaxf(hacc[2] + b1v.z, 0.f);
      float v3 = fmaxf(hacc[3] + b1v.w, 0.f);
      uint2 p;
      p.x = f2bf(v0) | (f2bf(v1) << 16);
      p.y = f2bf(v2) | (f2bf(v3) << 16);
      *(uint2*)(htw + l15*80 + hs*32 + lg*8) = p;            // ht[tok][h-linear]
    }
    // stage 2: y[16tok x 128o] += relu(h) @ w2 ; A from ht, B from w2s (same k-mapping)
    bf16x8 afrag = *(const bf16x8*)(htw + l15*80 + lg*16);
    #pragma unroll
    for (int ot = 0; ot < 8; ++ot){
      bf16x8 bfrag = *(const bf16x8*)(w2s + (ot*16 + l15)*80 + lg*16);
      yacc[ot] = __builtin_amdgcn_mfma_f32_16x16x32_bf16(afrag, bfrag, yacc[ot], 0, 0, 0);
    }
  }
  // epilogue: D: o = ot*16 + (lane&15), tok = 4*(lane>>4)+reg ; coalesced gate-scaled atomics
  float b2v[8];
  #pragma unroll
  for (int ot = 0; ot < 8; ++ot) b2v[ot] = b2[e*NO + ot*16 + l15];
  int s4 = base + wid*16 + lg*4;
  #pragma unroll
  for (int r = 0; r < 4; ++r){
    int slot = s4 + r;
    if (slot < n_e){
      int tokg = tid_e[slot];
      float g  = tg_e[slot];
      float* yrow = y + (size_t)tokg*NO + l15;
      #pragma unroll
      for (int ot = 0; ot < 8; ++ot)
        atomicAdd(yrow + ot*16, (yacc[ot][r] + b2v[ot]) * g);
    }
  }
}

__global__ void loss_kernel(const int* __restrict__ counts, const float* __restrict__ imp,
                            float* __restrict__ out){
  if (threadIdx.x != 0) return;
  double si = 0, sqi = 0, sl = 0, sql = 0;
  for (int e = 0; e < NE; ++e){
    double a = imp[e*CPAD];
    double b = (double)counts[e*CPAD];
    si += a; sqi += a*a; sl += b; sql += b*b;
  }
  double mi = si/8.0, vi = (sqi - 8.0*mi*mi)/7.0;
  double ml = sl/8.0, vl = (sql - 8.0*ml*ml)/7.0;
  out[NB*NO] = (float)(vi/(mi*mi + 1e-10) + vl/(ml*ml + 1e-10));
}

extern "C" void kernel_launch(void* const* d_in, const int* in_sizes, int n_in,
                              void* d_out, int out_size, void* d_ws, size_t ws_size,
                              hipStream_t stream){
  (void)in_sizes; (void)n_in; (void)out_size; (void)ws_size;
  const float* x  = (const float*)d_in[0];
  const float* wg = (const float*)d_in[1];
  const float* w1 = (const float*)d_in[2];
  const float* b1 = (const float*)d_in[3];
  const float* w2 = (const float*)d_in[4];
  const float* b2 = (const float*)d_in[5];
  float* out = (float*)d_out;
  char* ws = (char*)d_ws;
  int*            counts   = (int*)(ws + WS_COUNTS);
  float*          imp      = (float*)(ws + WS_IMP);
  int*            tok_ids  = (int*)(ws + WS_TOKID);
  float*          tok_gate = (float*)(ws + WS_TOKGATE);
  unsigned short* xbf      = (unsigned short*)(ws + WS_XBF);
  unsigned short* w1t      = (unsigned short*)(ws + WS_W1T);
  unsigned short* w2t      = (unsigned short*)(ws + WS_W2T);

  hipMemsetAsync(d_out, 0, (size_t)(NB*NO + 1)*sizeof(float), stream);
  hipMemsetAsync(d_ws, 0, 2048, stream);
  gating_kernel<<<NB/64, 256, 0, stream>>>(x, wg, xbf, counts, imp, tok_ids, tok_gate);
  transpose_bf16_kernel<<<dim3(8, 2, NE), 256, 0, stream>>>(w1, w1t, ND, NH);
  transpose_bf16_kernel<<<dim3(2, 8, NE), 256, 0, stream>>>(w2, w2t, NH, NO);
  expert_kernel<<<dim3(NB/64, NE), 256, 0, stream>>>(xbf, w1t, w2t, b1, b2,
                                                     counts, tok_ids, tok_gate, out);
  loss_kernel<<<1, 64, 0, stream>>>(counts, imp, out);
}

// Round 3
// 56.641 us; speedup vs baseline: 5.9078x; 1.2632x over previous
//
#include <hip/hip_runtime.h>
#include <hip/hip_bf16.h>
#include <math.h>

#define NB 16384
#define ND 128
#define NH 512
#define NO 128
#define NE 8
#define CPAD 32
#define NCH 8                 // chunks of 64 h
#define EPSF 2.2204460492503131e-16f

using bf16x8 = __attribute__((ext_vector_type(8))) short;
using f32x16 = __attribute__((ext_vector_type(16))) float;
using uint2v = __attribute__((ext_vector_type(2))) unsigned;

// ---- workspace layout (bytes) ----
#define WS_COUNTS 0u                       // int  [NE*CPAD]
#define WS_IMP    1024u                    // float[NE*CPAD]
#define WS_TOKID  2048u                    // int  [NE][NB]  (tok | which<<30)
#define WS_TOKGG  526336u                  // float2[NB]
#define WS_XBF    657408u                  // ushort[NB][ND]
#define WS_W1F    4851712u                 // ushort, frag-linear w1 (1MB)
#define WS_W2F    5900288u                 // ushort, frag-linear w2 (1MB)
#define WS_YSTAGE 6948864u                 // float[NB][2][NO] (16.8MB)

__device__ __forceinline__ unsigned f2bf(float f){
  unsigned u = __float_as_uint(f);
  u += 0x7FFFu + ((u >> 16) & 1u);
  return u >> 16;
}
__device__ __forceinline__ unsigned cvtpk(float lo, float hi){
  unsigned r;
  asm("v_cvt_pk_bf16_f32 %0, %1, %2" : "=v"(r) : "v"(lo), "v"(hi));
  return r;
}
__device__ __forceinline__ void gld16(const void* g, void* l){
  __builtin_amdgcn_global_load_lds((const __attribute__((address_space(1))) void*)g,
                                   (__attribute__((address_space(3))) void*)l, 16, 0, 0);
}

// ============ prep: gating (blocks 0-255) + w1 frag-pack (256-511) + w2 frag-pack (512-767)
__global__ __launch_bounds__(256) void prep_kernel(
    const float* __restrict__ x, const float* __restrict__ wg,
    const float* __restrict__ w1, const float* __restrict__ w2,
    unsigned short* __restrict__ xbf, unsigned short* __restrict__ w1f,
    unsigned short* __restrict__ w2f, int* __restrict__ counts,
    float* __restrict__ imp, int* __restrict__ tok_ids, float2* __restrict__ tok_gg){
  int bx = blockIdx.x, tid = threadIdx.x;
  if (bx >= 512){            // ---- w2 pack: w2f[e][c][hb(8)][o(128)][8] <- w2[e][h][o]
    int u = (bx - 512)*256 + tid;
    int o = u & 127, hb = (u>>7)&7, c = (u>>10)&7, e = u>>13;
    int h0 = c*64 + (hb>>1)*16 + (hb&1)*8;
    const float* src = w2 + (size_t)e*NH*NO + (size_t)h0*NO + o;
    unsigned q[4];
    #pragma unroll
    for (int p = 0; p < 4; ++p)
      q[p] = f2bf(src[(2*p)*NO]) | (f2bf(src[(2*p+1)*NO]) << 16);
    *(uint4*)(w2f + (size_t)u*8) = make_uint4(q[0], q[1], q[2], q[3]);
    return;
  }
  if (bx >= 256){            // ---- w1 pack: w1f[e][c][hf(2)][db(16)][h32(32)][8] <- w1[e][d][h]
    int u = (bx - 256)*256 + tid;
    int h32 = u & 31, db = (u>>5)&15, hf = (u>>9)&1, c = (u>>10)&7, e = u>>13;
    int d0 = (db>>1)*16 + (db&1)*8;
    int hg = c*64 + hf*32 + h32;
    const float* src = w1 + (size_t)e*ND*NH + (size_t)d0*NH + hg;
    unsigned q[4];
    #pragma unroll
    for (int p = 0; p < 4; ++p)
      q[p] = f2bf(src[(2*p)*NH]) | (f2bf(src[(2*p+1)*NH]) << 16);
    *(uint4*)(w1f + (size_t)u*8) = make_uint4(q[0], q[1], q[2], q[3]);
    return;
  }
  // ---- gating: 64 tokens/block, 4 lanes per token, f64 logits
  __shared__ int   lcnt[NE];
  __shared__ float limp[NE];
  __shared__ int   lbase[NE];
  if (tid < NE){ lcnt[tid] = 0; limp[tid] = 0.f; }
  __syncthreads();
  int tok  = bx*64 + (tid >> 2);
  int part = tid & 3;
  const float4* xr4 = (const float4*)(x + (size_t)tok*ND);
  double acc[NE];
  #pragma unroll
  for (int e = 0; e < NE; ++e) acc[e] = 0.0;
  #pragma unroll
  for (int j = 0; j < 8; ++j){
    int f4 = part + j*4;
    float4 v = xr4[f4];
    uint2 p;
    p.x = f2bf(v.x) | (f2bf(v.y) << 16);
    p.y = f2bf(v.z) | (f2bf(v.w) << 16);
    *(uint2*)(xbf + (size_t)tok*ND + f4*4) = p;
    const float4* wr = (const float4*)(wg + f4*32);
    float vm[4] = {v.x, v.y, v.z, v.w};
    #pragma unroll
    for (int m = 0; m < 4; ++m){
      float4 wa = wr[2*m], wb = wr[2*m+1];
      double d = (double)vm[m];
      acc[0] += d*(double)wa.x; acc[1] += d*(double)wa.y;
      acc[2] += d*(double)wa.z; acc[3] += d*(double)wa.w;
      acc[4] += d*(double)wb.x; acc[5] += d*(double)wb.y;
      acc[6] += d*(double)wb.z; acc[7] += d*(double)wb.w;
    }
  }
  #pragma unroll
  for (int e = 0; e < NE; ++e){
    acc[e] += __shfl_xor(acc[e], 1);
    acc[e] += __shfl_xor(acc[e], 2);
  }
  int i0 = 0, i1 = 0, s0 = 0, s1 = 0;
  float g0 = 0.f, g1 = 0.f;
  if (part == 0){
    double l0 = acc[0];
    #pragma unroll
    for (int e = 1; e < NE; ++e) if (acc[e] > l0){ l0 = acc[e]; i0 = e; }
    i1 = (i0 == 0) ? 1 : 0;
    double l1 = acc[i1];
    #pragma unroll
    for (int e = 0; e < NE; ++e) if (e != i0 && acc[e] > l1){ l1 = acc[e]; i1 = e; }
    float e1 = expf((float)(l1 - l0));
    g0 = 1.0f/(1.0f + e1);
    g1 = e1/(1.0f + e1);
    s0 = atomicAdd(&lcnt[i0], 1);
    s1 = atomicAdd(&lcnt[i1], 1);
    atomicAdd(&limp[i0], g0);
    atomicAdd(&limp[i1], g1);
    tok_gg[tok] = make_float2(g0, g1);
  }
  __syncthreads();
  if (tid < NE){
    lbase[tid] = atomicAdd(&counts[tid*CPAD], lcnt[tid]);
    atomicAdd(&imp[tid*CPAD], limp[tid]);
  }
  __syncthreads();
  if (part == 0){
    tok_ids[i0*NB + lbase[i0] + s0] = tok;
    tok_ids[i1*NB + lbase[i1] + s1] = tok | (1 << 30);
  }
}

// ============ experts: 128 tok/block, 4 waves x 32-tok Mfrag, 32x32x16 MFMA,
// frag-linear LDS staging (conflict-free), ht kept in-register via cvt_pk+permlane32_swap.
__global__ __launch_bounds__(256) void expert_kernel(
    const unsigned short* __restrict__ xbf, const unsigned short* __restrict__ w1f,
    const unsigned short* __restrict__ w2f, const float* __restrict__ b1,
    const float* __restrict__ b2, const int* __restrict__ counts,
    const int* __restrict__ tok_ids, float* __restrict__ ystage){
  __shared__ char smem[65536];               // w1buf[2][16K] | w2buf[2][16K]
  int e = blockIdx.y;
  int n_e = counts[e*CPAD];
  int base = blockIdx.x*128;
  if (base >= n_e) return;
  int tid = threadIdx.x, wid = tid >> 6, lane = tid & 63, l31 = lane & 31, hi = lane >> 5;
  const int* tid_e = tok_ids + e*NB;
  char* w1buf = smem;
  char* w2buf = smem + 32768;
  const char* g1base = (const char*)w1f + ((size_t)e*NCH)*16384;
  const char* g2base = (const char*)w2f + ((size_t)e*NCH)*16384;

  int slot0 = base + wid*32 + l31;
  int raw0 = tid_e[slot0 < n_e ? slot0 : n_e-1];
  int tok0 = raw0 & 0x3FFFFFFF;
  bf16x8 xfrag[8];
  #pragma unroll
  for (int k = 0; k < 8; ++k)
    xfrag[k] = *(const bf16x8*)(xbf + (size_t)tok0*ND + (k*2 + hi)*8);

#define STAGE(c, bsel) do { \
    const char* _g1 = g1base + (size_t)(c)*16384 + wid*1024 + lane*16; \
    const char* _g2 = g2base + (size_t)(c)*16384 + wid*1024 + lane*16; \
    char* _l1 = w1buf + (bsel)*16384 + wid*1024; \
    char* _l2 = w2buf + (bsel)*16384 + wid*1024; \
    _Pragma("unroll") \
    for (int _s = 0; _s < 4; ++_s){ \
      gld16(_g1 + _s*4096, _l1 + _s*4096); \
      gld16(_g2 + _s*4096, _l2 + _s*4096); \
    } \
  } while(0)

  STAGE(0, 0);
  f32x16 yacc[4];
  #pragma unroll
  for (int ot = 0; ot < 4; ++ot)
    #pragma unroll
    for (int i = 0; i < 16; ++i) yacc[ot][i] = 0.f;
  __syncthreads();

  for (int c = 0; c < NCH; ++c){
    int b = c & 1;
    if (c + 1 < NCH) STAGE(c + 1, b ^ 1);
    bf16x8 aht[4];
    #pragma unroll
    for (int hf = 0; hf < 2; ++hf){
      f32x16 hacc;
      #pragma unroll
      for (int i = 0; i < 16; ++i) hacc[i] = 0.f;
      #pragma unroll
      for (int k = 0; k < 8; ++k){
        bf16x8 a = *(const bf16x8*)(w1buf + b*16384 + hf*8192 + (k*2 + hi)*512 + l31*16);
        hacc = __builtin_amdgcn_mfma_f32_32x32x16_bf16(a, xfrag[k], hacc, 0, 0, 0);
      }
      const float4* b1p = (const float4*)(b1 + e*NH + c*64 + hf*32 + hi*4);
      float dv[16];
      #pragma unroll
      for (int g = 0; g < 4; ++g){
        float4 bv = b1p[2*g];
        dv[4*g+0] = fmaxf(hacc[4*g+0] + bv.x, 0.f);
        dv[4*g+1] = fmaxf(hacc[4*g+1] + bv.y, 0.f);
        dv[4*g+2] = fmaxf(hacc[4*g+2] + bv.z, 0.f);
        dv[4*g+3] = fmaxf(hacc[4*g+3] + bv.w, 0.f);
      }
      unsigned A0 = cvtpk(dv[0], dv[1]),  A1 = cvtpk(dv[2], dv[3]);
      unsigned A2 = cvtpk(dv[4], dv[5]),  A3 = cvtpk(dv[6], dv[7]);
      unsigned A4 = cvtpk(dv[8], dv[9]),  A5 = cvtpk(dv[10], dv[11]);
      unsigned A6 = cvtpk(dv[12], dv[13]), A7 = cvtpk(dv[14], dv[15]);
      uint2v r0 = __builtin_amdgcn_permlane32_swap(A0, A2, false, false);
      uint2v r1 = __builtin_amdgcn_permlane32_swap(A1, A3, false, false);
      uint2v r2 = __builtin_amdgcn_permlane32_swap(A4, A6, false, false);
      uint2v r3 = __builtin_amdgcn_permlane32_swap(A5, A7, false, false);
      union { unsigned u[4]; bf16x8 v; } fa, fb;
      fa.u[0] = r0[0]; fa.u[1] = r1[0]; fa.u[2] = r0[1]; fa.u[3] = r1[1];
      fb.u[0] = r2[0]; fb.u[1] = r3[0]; fb.u[2] = r2[1]; fb.u[3] = r3[1];
      aht[hf*2 + 0] = fa.v;
      aht[hf*2 + 1] = fb.v;
    }
    #pragma unroll
    for (int ot = 0; ot < 4; ++ot)
      #pragma unroll
      for (int kk = 0; kk < 4; ++kk){
        bf16x8 bfr = *(const bf16x8*)(w2buf + b*16384 + (kk*2 + hi)*2048 + (ot*32 + l31)*16);
        yacc[ot] = __builtin_amdgcn_mfma_f32_32x32x16_bf16(aht[kk], bfr, yacc[ot], 0, 0, 0);
      }
    __syncthreads();
  }
#undef STAGE
  float b2v[4];
  #pragma unroll
  for (int ot = 0; ot < 4; ++ot) b2v[ot] = b2[e*NO + ot*32 + l31];
  #pragma unroll
  for (int r = 0; r < 16; ++r){
    int row = (r & 3) + 8*(r >> 2) + 4*hi;
    int slot = base + wid*32 + row;
    if (slot < n_e){
      int rw = tid_e[slot];
      int tk = rw & 0x3FFFFFFF, wh = (rw >> 30) & 1;
      float* dst = ystage + ((size_t)tk*2 + wh)*NO + l31;
      #pragma unroll
      for (int ot = 0; ot < 4; ++ot)
        dst[ot*32] = yacc[ot][r] + b2v[ot];
    }
  }
}

// ============ combine: y[tok] = g0*row0 + g1*row1, eps-fix; loss in block 0
__global__ __launch_bounds__(256) void combine_kernel(
    const float* __restrict__ ystage, const float2* __restrict__ tok_gg,
    const int* __restrict__ counts, const float* __restrict__ imp,
    float* __restrict__ y){
  if (blockIdx.x == 0 && threadIdx.x == 0){
    double si = 0, sqi = 0, sl = 0, sql = 0;
    for (int e = 0; e < NE; ++e){
      double a = imp[e*CPAD];
      double b = (double)counts[e*CPAD];
      si += a; sqi += a*a; sl += b; sql += b*b;
    }
    double mi = si/8.0, vi = (sqi - 8.0*mi*mi)/7.0;
    double ml = sl/8.0, vl = (sql - 8.0*ml*ml)/7.0;
    y[NB*NO] = (float)(vi/(mi*mi + 1e-10) + vl/(ml*ml + 1e-10));
  }
  int idx = blockIdx.x*256 + threadIdx.x;    // 524288 threads, 4 floats each
  int tk = idx >> 5, q = idx & 31;
  float2 gg = tok_gg[tk];
  float4 a = *(const float4*)(ystage + (size_t)tk*256 + q*4);
  float4 b = *(const float4*)(ystage + (size_t)tk*256 + 128 + q*4);
  float4 v;
  v.x = gg.x*a.x + gg.y*b.x;  v.x = (v.x == 0.f) ? EPSF : v.x;
  v.y = gg.x*a.y + gg.y*b.y;  v.y = (v.y == 0.f) ? EPSF : v.y;
  v.z = gg.x*a.z + gg.y*b.z;  v.z = (v.z == 0.f) ? EPSF : v.z;
  v.w = gg.x*a.w + gg.y*b.w;  v.w = (v.w == 0.f) ? EPSF : v.w;
  *(float4*)(y + (size_t)tk*128 + q*4) = v;
}

extern "C" void kernel_launch(void* const* d_in, const int* in_sizes, int n_in,
                              void* d_out, int out_size, void* d_ws, size_t ws_size,
                              hipStream_t stream){
  (void)in_sizes; (void)n_in; (void)out_size; (void)ws_size;
  const float* x  = (const float*)d_in[0];
  const float* wg = (const float*)d_in[1];
  const float* w1 = (const float*)d_in[2];
  const float* b1 = (const float*)d_in[3];
  const float* w2 = (const float*)d_in[4];
  const float* b2 = (const float*)d_in[5];
  float* out = (float*)d_out;
  char* ws = (char*)d_ws;
  int*            counts  = (int*)(ws + WS_COUNTS);
  float*          imp     = (float*)(ws + WS_IMP);
  int*            tok_ids = (int*)(ws + WS_TOKID);
  float2*         tok_gg  = (float2*)(ws + WS_TOKGG);
  unsigned short* xbf     = (unsigned short*)(ws + WS_XBF);
  unsigned short* w1f     = (unsigned short*)(ws + WS_W1F);
  unsigned short* w2f     = (unsigned short*)(ws + WS_W2F);
  float*          ystage  = (float*)(ws + WS_YSTAGE);

  hipMemsetAsync(d_ws, 0, 2048, stream);
  prep_kernel<<<768, 256, 0, stream>>>(x, wg, w1, w2, xbf, w1f, w2f,
                                       counts, imp, tok_ids, tok_gg);
  expert_kernel<<<dim3(128, NE), 256, 0, stream>>>(xbf, w1f, w2f, b1, b2,
                                                   counts, tok_ids, ystage);
  combine_kernel<<<2048, 256, 0, stream>>>(ystage, tok_gg, counts, imp, out);
}

// Round 4
// 56.116 us; speedup vs baseline: 5.9630x; 1.0094x over previous
//
#include <hip/hip_runtime.h>
#include <hip/hip_bf16.h>
#include <math.h>

#define NB 16384
#define ND 128
#define NH 512
#define NO 128
#define NE 8
#define CPAD 32
#define NCH 8                 // chunks of 64 h
#define EPSF 2.2204460492503131e-16f

using bf16x8 = __attribute__((ext_vector_type(8))) short;
using f32x16 = __attribute__((ext_vector_type(16))) float;
using uint2v = __attribute__((ext_vector_type(2))) unsigned;

// ---- workspace layout (bytes) ----
#define WS_COUNTS 0u                       // int  [NE*CPAD]
#define WS_IMP    1024u                    // float[NE*CPAD]
#define WS_TOKID  2048u                    // int  [NE][NB]  (tok | which<<30)
#define WS_TOKGG  526336u                  // float2[NB]
#define WS_XBF    657408u                  // ushort[NB][ND]
#define WS_W1F    4851712u                 // ushort, frag-linear w1 (1MB)
#define WS_W2F    5900288u                 // ushort, frag-linear w2 (1MB)
#define WS_YSTAGE 6948864u                 // float[NB][2][NO] (16.8MB)

__device__ __forceinline__ unsigned f2bf(float f){
  unsigned u = __float_as_uint(f);
  u += 0x7FFFu + ((u >> 16) & 1u);
  return u >> 16;
}
__device__ __forceinline__ unsigned cvtpk(float lo, float hi){
  unsigned r;
  asm("v_cvt_pk_bf16_f32 %0, %1, %2" : "=v"(r) : "v"(lo), "v"(hi));
  return r;
}
__device__ __forceinline__ void gld16(const void* g, void* l){
  __builtin_amdgcn_global_load_lds((const __attribute__((address_space(1))) void*)g,
                                   (__attribute__((address_space(3))) void*)l, 16, 0, 0);
}

// ============ prep: gating (blocks 0-255) + w1 frag-pack (256-511) + w2 frag-pack (512-767)
__global__ __launch_bounds__(256) void prep_kernel(
    const float* __restrict__ x, const float* __restrict__ wg,
    const float* __restrict__ w1, const float* __restrict__ w2,
    unsigned short* __restrict__ xbf, unsigned short* __restrict__ w1f,
    unsigned short* __restrict__ w2f, int* __restrict__ counts,
    float* __restrict__ imp, int* __restrict__ tok_ids, float2* __restrict__ tok_gg){
  int bx = blockIdx.x, tid = threadIdx.x;
  if (bx >= 512){            // ---- w2 pack: w2f[e][c][hb(8)][o(128)][8] <- w2[e][h][o]
    int u = (bx - 512)*256 + tid;
    int o = u & 127, hb = (u>>7)&7, c = (u>>10)&7, e = u>>13;
    int h0 = c*64 + (hb>>1)*16 + (hb&1)*8;
    const float* src = w2 + (size_t)e*NH*NO + (size_t)h0*NO + o;
    unsigned q[4];
    #pragma unroll
    for (int p = 0; p < 4; ++p)
      q[p] = f2bf(src[(2*p)*NO]) | (f2bf(src[(2*p+1)*NO]) << 16);
    *(uint4*)(w2f + (size_t)u*8) = make_uint4(q[0], q[1], q[2], q[3]);
    return;
  }
  if (bx >= 256){            // ---- w1 pack: w1f[e][c][hf(2)][db(16)][h32(32)][8] <- w1[e][d][h]
    int u = (bx - 256)*256 + tid;
    int h32 = u & 31, db = (u>>5)&15, hf = (u>>9)&1, c = (u>>10)&7, e = u>>13;
    int d0 = (db>>1)*16 + (db&1)*8;
    int hg = c*64 + hf*32 + h32;
    const float* src = w1 + (size_t)e*ND*NH + (size_t)d0*NH + hg;
    unsigned q[4];
    #pragma unroll
    for (int p = 0; p < 4; ++p)
      q[p] = f2bf(src[(2*p)*NH]) | (f2bf(src[(2*p+1)*NH]) << 16);
    *(uint4*)(w1f + (size_t)u*8) = make_uint4(q[0], q[1], q[2], q[3]);
    return;
  }
  // ---- gating: 64 tokens/block, 4 lanes per token, f64 logits
  __shared__ int   lcnt[NE];
  __shared__ float limp[NE];
  __shared__ int   lbase[NE];
  if (tid < NE){ lcnt[tid] = 0; limp[tid] = 0.f; }
  __syncthreads();
  int tok  = bx*64 + (tid >> 2);
  int part = tid & 3;
  const float4* xr4 = (const float4*)(x + (size_t)tok*ND);
  double acc[NE];
  #pragma unroll
  for (int e = 0; e < NE; ++e) acc[e] = 0.0;
  #pragma unroll
  for (int j = 0; j < 8; ++j){
    int f4 = part + j*4;
    float4 v = xr4[f4];
    uint2 p;
    p.x = f2bf(v.x) | (f2bf(v.y) << 16);
    p.y = f2bf(v.z) | (f2bf(v.w) << 16);
    *(uint2*)(xbf + (size_t)tok*ND + f4*4) = p;
    const float4* wr = (const float4*)(wg + f4*32);
    float vm[4] = {v.x, v.y, v.z, v.w};
    #pragma unroll
    for (int m = 0; m < 4; ++m){
      float4 wa = wr[2*m], wb = wr[2*m+1];
      double d = (double)vm[m];
      acc[0] += d*(double)wa.x; acc[1] += d*(double)wa.y;
      acc[2] += d*(double)wa.z; acc[3] += d*(double)wa.w;
      acc[4] += d*(double)wb.x; acc[5] += d*(double)wb.y;
      acc[6] += d*(double)wb.z; acc[7] += d*(double)wb.w;
    }
  }
  #pragma unroll
  for (int e = 0; e < NE; ++e){
    acc[e] += __shfl_xor(acc[e], 1);
    acc[e] += __shfl_xor(acc[e], 2);
  }
  int i0 = 0, i1 = 0, s0 = 0, s1 = 0;
  float g0 = 0.f, g1 = 0.f;
  if (part == 0){
    double l0 = acc[0];
    #pragma unroll
    for (int e = 1; e < NE; ++e) if (acc[e] > l0){ l0 = acc[e]; i0 = e; }
    i1 = (i0 == 0) ? 1 : 0;
    double l1 = acc[i1];
    #pragma unroll
    for (int e = 0; e < NE; ++e) if (e != i0 && acc[e] > l1){ l1 = acc[e]; i1 = e; }
    float e1 = expf((float)(l1 - l0));
    g0 = 1.0f/(1.0f + e1);
    g1 = e1/(1.0f + e1);
    s0 = atomicAdd(&lcnt[i0], 1);
    s1 = atomicAdd(&lcnt[i1], 1);
    atomicAdd(&limp[i0], g0);
    atomicAdd(&limp[i1], g1);
    tok_gg[tok] = make_float2(g0, g1);
  }
  __syncthreads();
  if (tid < NE){
    lbase[tid] = atomicAdd(&counts[tid*CPAD], lcnt[tid]);
    atomicAdd(&imp[tid*CPAD], limp[tid]);
  }
  __syncthreads();
  if (part == 0){
    tok_ids[i0*NB + lbase[i0] + s0] = tok;
    tok_ids[i1*NB + lbase[i1] + s1] = tok | (1 << 30);
  }
}

// ============ experts: 128 tok/block, 4 waves x 32-tok Mfrag, 32x32x16 MFMA,
// frag-linear LDS staging (conflict-free), ht kept in-register via cvt_pk+permlane32_swap.
__global__ __launch_bounds__(256) void expert_kernel(
    const unsigned short* __restrict__ xbf, const unsigned short* __restrict__ w1f,
    const unsigned short* __restrict__ w2f, const float* __restrict__ b1,
    const float* __restrict__ b2, const int* __restrict__ counts,
    const int* __restrict__ tok_ids, float* __restrict__ ystage){
  __shared__ char smem[65536];               // w1buf[2][16K] | w2buf[2][16K]
  int e = blockIdx.y;
  int n_e = counts[e*CPAD];
  int base = blockIdx.x*128;
  if (base >= n_e) return;
  int tid = threadIdx.x, wid = tid >> 6, lane = tid & 63, l31 = lane & 31, hi = lane >> 5;
  const int* tid_e = tok_ids + e*NB;
  char* w1buf = smem;
  char* w2buf = smem + 32768;
  const char* g1base = (const char*)w1f + ((size_t)e*NCH)*16384;
  const char* g2base = (const char*)w2f + ((size_t)e*NCH)*16384;

  int slot0 = base + wid*32 + l31;
  int raw0 = tid_e[slot0 < n_e ? slot0 : n_e-1];
  int tok0 = raw0 & 0x3FFFFFFF;
  bf16x8 xfrag[8];
  #pragma unroll
  for (int k = 0; k < 8; ++k)
    xfrag[k] = *(const bf16x8*)(xbf + (size_t)tok0*ND + (k*2 + hi)*8);

#define STAGE(c, bsel) do { \
    const char* _g1 = g1base + (size_t)(c)*16384 + wid*1024 + lane*16; \
    const char* _g2 = g2base + (size_t)(c)*16384 + wid*1024 + lane*16; \
    char* _l1 = w1buf + (bsel)*16384 + wid*1024; \
    char* _l2 = w2buf + (bsel)*16384 + wid*1024; \
    _Pragma("unroll") \
    for (int _s = 0; _s < 4; ++_s){ \
      gld16(_g1 + _s*4096, _l1 + _s*4096); \
      gld16(_g2 + _s*4096, _l2 + _s*4096); \
    } \
  } while(0)

  STAGE(0, 0);
  f32x16 yacc[4];
  #pragma unroll
  for (int ot = 0; ot < 4; ++ot)
    #pragma unroll
    for (int i = 0; i < 16; ++i) yacc[ot][i] = 0.f;
  __syncthreads();

  for (int c = 0; c < NCH; ++c){
    int b = c & 1;
    if (c + 1 < NCH) STAGE(c + 1, b ^ 1);
    bf16x8 aht[4];
    #pragma unroll
    for (int hf = 0; hf < 2; ++hf){
      f32x16 hacc;
      #pragma unroll
      for (int i = 0; i < 16; ++i) hacc[i] = 0.f;
      #pragma unroll
      for (int k = 0; k < 8; ++k){
        bf16x8 a = *(const bf16x8*)(w1buf + b*16384 + hf*8192 + (k*2 + hi)*512 + l31*16);
        hacc = __builtin_amdgcn_mfma_f32_32x32x16_bf16(a, xfrag[k], hacc, 0, 0, 0);
      }
      const float4* b1p = (const float4*)(b1 + e*NH + c*64 + hf*32 + hi*4);
      float dv[16];
      #pragma unroll
      for (int g = 0; g < 4; ++g){
        float4 bv = b1p[2*g];
        dv[4*g+0] = fmaxf(hacc[4*g+0] + bv.x, 0.f);
        dv[4*g+1] = fmaxf(hacc[4*g+1] + bv.y, 0.f);
        dv[4*g+2] = fmaxf(hacc[4*g+2] + bv.z, 0.f);
        dv[4*g+3] = fmaxf(hacc[4*g+3] + bv.w, 0.f);
      }
      unsigned A0 = cvtpk(dv[0], dv[1]),  A1 = cvtpk(dv[2], dv[3]);
      unsigned A2 = cvtpk(dv[4], dv[5]),  A3 = cvtpk(dv[6], dv[7]);
      unsigned A4 = cvtpk(dv[8], dv[9]),  A5 = cvtpk(dv[10], dv[11]);
      unsigned A6 = cvtpk(dv[12], dv[13]), A7 = cvtpk(dv[14], dv[15]);
      uint2v r0 = __builtin_amdgcn_permlane32_swap(A0, A2, false, false);
      uint2v r1 = __builtin_amdgcn_permlane32_swap(A1, A3, false, false);
      uint2v r2 = __builtin_amdgcn_permlane32_swap(A4, A6, false, false);
      uint2v r3 = __builtin_amdgcn_permlane32_swap(A5, A7, false, false);
      union { unsigned u[4]; bf16x8 v; } fa, fb;
      fa.u[0] = r0[0]; fa.u[1] = r1[0]; fa.u[2] = r0[1]; fa.u[3] = r1[1];
      fb.u[0] = r2[0]; fb.u[1] = r3[0]; fb.u[2] = r2[1]; fb.u[3] = r3[1];
      aht[hf*2 + 0] = fa.v;
      aht[hf*2 + 1] = fb.v;
    }
    #pragma unroll
    for (int ot = 0; ot < 4; ++ot)
      #pragma unroll
      for (int kk = 0; kk < 4; ++kk){
        bf16x8 bfr = *(const bf16x8*)(w2buf + b*16384 + (kk*2 + hi)*2048 + (ot*32 + l31)*16);
        yacc[ot] = __builtin_amdgcn_mfma_f32_32x32x16_bf16(aht[kk], bfr, yacc[ot], 0, 0, 0);
      }
    __syncthreads();
  }
#undef STAGE
  float b2v[4];
  #pragma unroll
  for (int ot = 0; ot < 4; ++ot) b2v[ot] = b2[e*NO + ot*32 + l31];
  #pragma unroll
  for (int r = 0; r < 16; ++r){
    int row = (r & 3) + 8*(r >> 2) + 4*hi;
    int slot = base + wid*32 + row;
    if (slot < n_e){
      int rw = tid_e[slot];
      int tk = rw & 0x3FFFFFFF, wh = (rw >> 30) & 1;
      float* dst = ystage + ((size_t)tk*2 + wh)*NO + l31;
      #pragma unroll
      for (int ot = 0; ot < 4; ++ot)
        dst[ot*32] = yacc[ot][r] + b2v[ot];
    }
  }
}

// ============ combine: y[tok] = g0*row0 + g1*row1, eps-fix; loss in block 0
__global__ __launch_bounds__(256) void combine_kernel(
    const float* __restrict__ ystage, const float2* __restrict__ tok_gg,
    const int* __restrict__ counts, const float* __restrict__ imp,
    float* __restrict__ y){
  if (blockIdx.x == 0 && threadIdx.x == 0){
    double si = 0, sqi = 0, sl = 0, sql = 0;
    for (int e = 0; e < NE; ++e){
      double a = imp[e*CPAD];
      double b = (double)counts[e*CPAD];
      si += a; sqi += a*a; sl += b; sql += b*b;
    }
    double mi = si/8.0, vi = (sqi - 8.0*mi*mi)/7.0;
    double ml = sl/8.0, vl = (sql - 8.0*ml*ml)/7.0;
    y[NB*NO] = (float)(vi/(mi*mi + 1e-10) + vl/(ml*ml + 1e-10));
  }
  int idx = blockIdx.x*256 + threadIdx.x;    // 524288 threads, 4 floats each
  int tk = idx >> 5, q = idx & 31;
  float2 gg = tok_gg[tk];
  float4 a = *(const float4*)(ystage + (size_t)tk*256 + q*4);
  float4 b = *(const float4*)(ystage + (size_t)tk*256 + 128 + q*4);
  float4 v;
  v.x = gg.x*a.x + gg.y*b.x;  v.x = (v.x == 0.f) ? EPSF : v.x;
  v.y = gg.x*a.y + gg.y*b.y;  v.y = (v.y == 0.f) ? EPSF : v.y;
  v.z = gg.x*a.z + gg.y*b.z;  v.z = (v.z == 0.f) ? EPSF : v.z;
  v.w = gg.x*a.w + gg.y*b.w;  v.w = (v.w == 0.f) ? EPSF : v.w;
  *(float4*)(y + (size_t)tk*128 + q*4) = v;
}

extern "C" void kernel_launch(void* const* d_in, const int* in_sizes, int n_in,
                              void* d_out, int out_size, void* d_ws, size_t ws_size,
                              hipStream_t stream){
  (void)in_sizes; (void)n_in; (void)out_size; (void)ws_size;
  const float* x  = (const float*)d_in[0];
  const float* wg = (const float*)d_in[1];
  const float* w1 = (const float*)d_in[2];
  const float* b1 = (const float*)d_in[3];
  const float* w2 = (const float*)d_in[4];
  const float* b2 = (const float*)d_in[5];
  float* out = (float*)d_out;
  char* ws = (char*)d_ws;
  int*            counts  = (int*)(ws + WS_COUNTS);
  float*          imp     = (float*)(ws + WS_IMP);
  int*            tok_ids = (int*)(ws + WS_TOKID);
  float2*         tok_gg  = (float2*)(ws + WS_TOKGG);
  unsigned short* xbf     = (unsigned short*)(ws + WS_XBF);
  unsigned short* w1f     = (unsigned short*)(ws + WS_W1F);
  unsigned short* w2f     = (unsigned short*)(ws + WS_W2F);
  float*          ystage  = (float*)(ws + WS_YSTAGE);

  hipMemsetAsync(d_ws, 0, 2048, stream);
  prep_kernel<<<768, 256, 0, stream>>>(x, wg, w1, w2, xbf, w1f, w2f,
                                       counts, imp, tok_ids, tok_gg);
  expert_kernel<<<dim3(128, NE), 256, 0, stream>>>(xbf, w1f, w2f, b1, b2,
                                                   counts, tok_ids, ystage);
  combine_kernel<<<2048, 256, 0, stream>>>(ystage, tok_gg, counts, imp, out);
}